// Round 2
// baseline (521.052 us; speedup 1.0000x reference)
//
#include <hip/hip_runtime.h>

#define COST_CLASS 1.0f
#define COST_BBOX  5.0f
#define COST_GIOU  2.0f
#define EPS 1e-6f

// Problem constants (from setup_inputs): B=32, Q=300, C=11, T=3200
constexpr int kC  = 11;
constexpr int TPB = 256;   // threads per block, each thread owns 4 consecutive targets
constexpr int NPT = 8;     // predictions per block

typedef float vf4 __attribute__((ext_vector_type(4)));

__device__ __forceinline__ float fast_rcp(float x) {
    return __builtin_amdgcn_rcpf(x);   // v_rcp_f32, ~1 ulp — fine vs 0.4 absmax threshold
}

// ---------------- Kernel A: per-prediction softmax (tiny) ----------------
__global__ void softmax_probs_kernel(const float* __restrict__ logits,
                                     float* __restrict__ probs, int N) {
    int n = blockIdx.x * blockDim.x + threadIdx.x;
    if (n >= N) return;
    float v[kC];
    float m = -1e30f;
#pragma unroll
    for (int c = 0; c < kC; ++c) {
        v[c] = logits[n * kC + c];
        m = fmaxf(m, v[c]);
    }
    float s = 0.f;
#pragma unroll
    for (int c = 0; c < kC; ++c) {
        v[c] = __expf(v[c] - m);
        s += v[c];
    }
    float inv = fast_rcp(s);
#pragma unroll
    for (int c = 0; c < kC; ++c) probs[n * kC + c] = v[c] * inv;
}

// ---------------- Kernel B: cost matrix + diagnostic variants ----------------
// MODE 0 = real kernel (bit-identical math to R1) -> out
// MODE 1 = store-only: same store pattern, ~1 VALU per element -> ws
// MODE 2 = compute-only: full VALU + DS bpermute, 1 store/thread -> sink
// MODE 3 = full compute minus class-gather (no rowp loads, no bpermute) -> ws
// REPEAT>1 repeats the work with per-pass perturbation (defeats CSE) and
// per-pass row rotation (defeats dead-store elim), so per-pass cost = dur/REPEAT.
template<int MODE, int REPEAT>
__global__ __launch_bounds__(TPB)
void cost_matrix_kernel(const float* __restrict__ probs,       // [N, C]
                        const float* __restrict__ pred_boxes,  // [N, 4] cxcywh
                        const int*   __restrict__ labels,      // [T]
                        const float* __restrict__ tboxes,      // [T, 4] cxcywh
                        float* __restrict__ out,               // [N, T]
                        float* __restrict__ sink,               // MODE 2 only
                        int N, int T) {
    int n0 = blockIdx.y * NPT;
    int lane = threadIdx.x & 63;

    // Load this block's 8 prob rows into lanes 0..10 (per wave).
    int rowp[NPT];
    if constexpr (MODE == 0 || MODE == 2) {
#pragma unroll
        for (int i = 0; i < NPT; ++i) {
            float p = 0.f;
            if (lane < kC) p = probs[(n0 + i) * kC + lane];
            rowp[i] = __float_as_int(p);
        }
    }

    int t4 = blockIdx.x * TPB + threadIdx.x;   // group of 4 targets
    if (t4 >= (T >> 2)) return;
    int tbase = t4 << 2;

    // --- load 4 targets into registers (reused across NPT preds) ---
    float4 tb[4];
    float tx0[4], ty0[4], tx1[4], ty1[4], tarea[4];
    int   labb[4];                              // lab*4 = bpermute byte index
    int4 labv = ((const int4*)labels)[t4];
    labb[0] = labv.x << 2; labb[1] = labv.y << 2;
    labb[2] = labv.z << 2; labb[3] = labv.w << 2;
#pragma unroll
    for (int j = 0; j < 4; ++j) {
        tb[j] = ((const float4*)tboxes)[tbase + j];
        tx0[j] = tb[j].x - 0.5f * tb[j].z;
        ty0[j] = tb[j].y - 0.5f * tb[j].w;
        tx1[j] = tb[j].x + 0.5f * tb[j].z;
        ty1[j] = tb[j].y + 0.5f * tb[j].w;
        tarea[j] = (tx1[j] - tx0[j]) * (ty1[j] - ty0[j]);
    }

    float acc = 0.f;   // MODE 2 keep-alive sink

#pragma unroll 1
    for (int r = 0; r < REPEAT; ++r) {
#pragma unroll
        for (int i = 0; i < NPT; ++i) {
            int n = n0 + i;
            float4 pb = ((const float4*)pred_boxes)[n];  // wave-uniform -> scalar load
            if constexpr (MODE != 0)
                pb.x += (float)r * 1e-20f;               // per-pass CSE breaker

            vf4 res;
            if constexpr (MODE == 1) {
                // store-only: touch the same inputs, trivial compute
                res[0] = tb[0].x + pb.x;
                res[1] = tb[1].y;
                res[2] = tb[2].z;
                res[3] = tb[3].w;
            } else {
                float p_x0 = pb.x - 0.5f * pb.z;
                float p_y0 = pb.y - 0.5f * pb.w;
                float p_x1 = pb.x + 0.5f * pb.z;
                float p_y1 = pb.y + 0.5f * pb.w;
                float p_area = (p_x1 - p_x0) * (p_y1 - p_y0);
#pragma unroll
                for (int j = 0; j < 4; ++j) {
                    float cb = fabsf(pb.x - tb[j].x) + fabsf(pb.y - tb[j].y) +
                               fabsf(pb.z - tb[j].z) + fabsf(pb.w - tb[j].w);
                    float lt_x = fmaxf(p_x0, tx0[j]), lt_y = fmaxf(p_y0, ty0[j]);
                    float rb_x = fminf(p_x1, tx1[j]), rb_y = fminf(p_y1, ty1[j]);
                    float iw = fmaxf(rb_x - lt_x, 0.f), ih = fmaxf(rb_y - lt_y, 0.f);
                    float inter = iw * ih;
                    float uni = p_area + tarea[j] - inter;
                    float iou = inter * fast_rcp(uni + EPS);
                    float cx0 = fminf(p_x0, tx0[j]), cy0 = fminf(p_y0, ty0[j]);
                    float cx1 = fmaxf(p_x1, tx1[j]), cy1 = fmaxf(p_y1, ty1[j]);
                    // boxes have w,h >= 0 -> enclosure extents provably >= 0
                    float cw = cx1 - cx0, ch = cy1 - cy0;
                    float carea = cw * ch;
                    float t2 = (carea - uni) * fast_rcp(carea + EPS);
                    float cc;
                    if constexpr (MODE == 0) {
                        cc = -__int_as_float(__builtin_amdgcn_ds_bpermute(labb[j], rowp[i]));
                    } else if constexpr (MODE == 2) {
                        // XOR keeps the 32 bpermutes inside the repeat loop
                        cc = -__int_as_float(__builtin_amdgcn_ds_bpermute(labb[j], rowp[i] ^ r));
                    } else {
                        cc = 0.f;   // MODE 3: no class gather
                    }
                    float rr = fmaf(COST_BBOX, cb, cc);
                    rr = fmaf(2.0f, t2, rr);
                    res[j] = fmaf(-2.0f, iou, rr);
                }
            }

            if constexpr (MODE == 2) {
                acc += res[0] + res[1] + res[2] + res[3];
            } else {
                int nn = n;
                if constexpr (MODE != 0) {
                    nn += r * NPT;               // rotate rows per pass: defeats DSE,
                    if (nn >= N) nn -= N;        // same footprint & coalescing
                }
                *(vf4*)(out + (size_t)nn * T + tbase) = res;
            }
        }
    }

    if constexpr (MODE == 2) {
        int gtid = (blockIdx.y * gridDim.x + blockIdx.x) * TPB + threadIdx.x;
        sink[gtid] = acc;
    }
}

extern "C" void kernel_launch(void* const* d_in, const int* in_sizes, int n_in,
                              void* d_out, int out_size, void* d_ws, size_t ws_size,
                              hipStream_t stream) {
    const float* class_logits  = (const float*)d_in[0];  // [B,Q,C]
    const float* bbox_coords   = (const float*)d_in[1];  // [B,Q,4]
    const int*   target_labels = (const int*)d_in[2];    // [T]
    const float* target_boxes  = (const float*)d_in[3];  // [T,4]
    float* out = (float*)d_out;

    int N = in_sizes[0] / kC;  // 9600
    int T = in_sizes[2];       // 3200

    float* probs = (float*)d_ws;                                   // 422 KB
    float* sink  = (float*)((char*)d_ws + (size_t)4  * 1024 * 1024); // 4.9 MB used
    float* vout  = (float*)((char*)d_ws + (size_t)16 * 1024 * 1024); // 122.9 MB used

    {
        int tpb = 256;
        int blocks = (N + tpb - 1) / tpb;
        softmax_probs_kernel<<<blocks, tpb, 0, stream>>>(class_logits, probs, N);
    }

    dim3 grid((T / 4 + TPB - 1) / TPB, N / NPT);

    // Diagnostic variants (workspace only; skipped if ws is unexpectedly small).
    // Poison fill shows ws+out = 491.5 MB -> ws ~ 368 MB, gate at 150 MB.
    if (ws_size >= (size_t)150 * 1024 * 1024) {
        cost_matrix_kernel<1, 5><<<grid, TPB, 0, stream>>>(probs, bbox_coords,
            target_labels, target_boxes, vout, sink, N, T);   // store-only x5
        cost_matrix_kernel<2, 6><<<grid, TPB, 0, stream>>>(probs, bbox_coords,
            target_labels, target_boxes, vout, sink, N, T);   // compute-only x6
        cost_matrix_kernel<3, 2><<<grid, TPB, 0, stream>>>(probs, bbox_coords,
            target_labels, target_boxes, vout, sink, N, T);   // no-gather x2
    }

    // Kernel of record — bit-identical math to R1, writes the real output.
    cost_matrix_kernel<0, 1><<<grid, TPB, 0, stream>>>(probs, bbox_coords,
        target_labels, target_boxes, out, sink, N, T);
}

// Round 3
// 149.430 us; speedup vs baseline: 3.4869x; 3.4869x over previous
//
#include <hip/hip_runtime.h>

#define COST_CLASS 1.0f
#define COST_BBOX  5.0f
#define COST_GIOU  2.0f
#define EPS 1e-6f

// Problem constants (from setup_inputs): B=32, Q=300, C=11, T=3200
constexpr int kC  = 11;
constexpr int TPB = 256;   // threads per block, each thread owns 4 consecutive targets
constexpr int NPT = 8;     // predictions per block

typedef float vf4 __attribute__((ext_vector_type(4)));
typedef float vf8 __attribute__((ext_vector_type(8)));

__device__ __forceinline__ float fast_rcp(float x) {
    return __builtin_amdgcn_rcpf(x);   // v_rcp_f32, ~1 ulp — fine vs 0.4 absmax threshold
}

// ---------------- Kernel A: softmax -> TRANSPOSED, pre-folded class cost ----
// Stores probsT[c][n] = 2 - softmax(logits[n])[c].
// The "2" comes from rewriting the GIoU term:
//   (carea-uni)/(carea+EPS) == 1 - (uni+EPS)/(carea+EPS)   (exact algebra)
// so cost = (2 - prob) + 5*L1 - 2*iou - 2*(uni+EPS)/(carea+EPS).
// Transposed layout lets kernel B fetch all NPT preds for one label with a
// single 32B vector load (row stride N*4 = 38400 B, 32B-aligned; n0 is a
// multiple of 8 -> column offset 32B-aligned).
// Writes stay coalesced: for fixed c, consecutive lanes write consecutive n.
__global__ void softmax_probsT_kernel(const float* __restrict__ logits,
                                      float* __restrict__ probsT, int N) {
    int n = blockIdx.x * blockDim.x + threadIdx.x;
    if (n >= N) return;
    float v[kC];
    float m = -1e30f;
#pragma unroll
    for (int c = 0; c < kC; ++c) {
        v[c] = logits[n * kC + c];
        m = fmaxf(m, v[c]);
    }
    float s = 0.f;
#pragma unroll
    for (int c = 0; c < kC; ++c) {
        v[c] = __expf(v[c] - m);
        s += v[c];
    }
    float inv = fast_rcp(s);
#pragma unroll
    for (int c = 0; c < kC; ++c)
        probsT[(size_t)c * N + n] = fmaf(-v[c], inv, 2.0f);   // 2 - prob
}

// ---------------- Kernel B: cost matrix ----------------
// R3: no LDS, no bpermute, no lgkmcnt in the hot loop. Class costs arrive as
// 4 independent 32B global loads (L1/L2-hot: whole probsT = 422 KB) issued at
// the top; inner loop is pure VALU + one vf4 store per pred.
// __launch_bounds__(TPB,4): cap VGPR at 128 -> 4 waves/SIMD (was 3 at 144),
// to cover the v_rcp chains and store backpressure the R2 ablation exposed.
__global__ __launch_bounds__(TPB, 4)
void cost_matrix_kernel(const float* __restrict__ probsT,      // [C, N] (=2-prob)
                        const float* __restrict__ pred_boxes,  // [N, 4] cxcywh
                        const int*   __restrict__ labels,      // [T]
                        const float* __restrict__ tboxes,      // [T, 4] cxcywh
                        float* __restrict__ out,               // [N, T]
                        int N, int T) {
    int n0 = blockIdx.y * NPT;
    int t4 = blockIdx.x * TPB + threadIdx.x;   // group of 4 targets
    if (t4 >= (T >> 2)) return;
    int tbase = t4 << 2;

    // --- class-cost vectors: probsT[lab[j]][n0..n0+7], one 32B load each ---
    int4 labv = ((const int4*)labels)[t4];
    const int labs[4] = {labv.x, labv.y, labv.z, labv.w};
    vf8 ccv[4];
#pragma unroll
    for (int j = 0; j < 4; ++j)
        ccv[j] = *(const vf8*)(probsT + (size_t)labs[j] * N + n0);

    // --- load 4 targets into registers (reused across NPT preds) ---
    float4 tb[4];
    float tx0[4], ty0[4], tx1[4], ty1[4], tarea[4];
#pragma unroll
    for (int j = 0; j < 4; ++j) {
        tb[j] = ((const float4*)tboxes)[tbase + j];
        tx0[j] = tb[j].x - 0.5f * tb[j].z;
        ty0[j] = tb[j].y - 0.5f * tb[j].w;
        tx1[j] = tb[j].x + 0.5f * tb[j].z;
        ty1[j] = tb[j].y + 0.5f * tb[j].w;
        tarea[j] = (tx1[j] - tx0[j]) * (ty1[j] - ty0[j]);
    }

#pragma unroll
    for (int i = 0; i < NPT; ++i) {
        int n = n0 + i;
        float4 pb = ((const float4*)pred_boxes)[n];  // wave-uniform -> scalar load
        float p_x0 = pb.x - 0.5f * pb.z;
        float p_y0 = pb.y - 0.5f * pb.w;
        float p_x1 = pb.x + 0.5f * pb.z;
        float p_y1 = pb.y + 0.5f * pb.w;
        float p_area = (p_x1 - p_x0) * (p_y1 - p_y0);

        vf4 res;
#pragma unroll
        for (int j = 0; j < 4; ++j) {
            // L1 on cxcywh (abs folds into VOP3 input modifiers)
            float cb = fabsf(pb.x - tb[j].x) + fabsf(pb.y - tb[j].y) +
                       fabsf(pb.z - tb[j].z) + fabsf(pb.w - tb[j].w);
            // GIoU pieces — divisions via v_rcp_f32
            float lt_x = fmaxf(p_x0, tx0[j]), lt_y = fmaxf(p_y0, ty0[j]);
            float rb_x = fminf(p_x1, tx1[j]), rb_y = fminf(p_y1, ty1[j]);
            float iw = fmaxf(rb_x - lt_x, 0.f), ih = fmaxf(rb_y - lt_y, 0.f);
            float inter = iw * ih;
            float u = p_area + tarea[j] - inter + EPS;   // union + EPS
            float iou = inter * fast_rcp(u);
            float cx0 = fminf(p_x0, tx0[j]), cy0 = fminf(p_y0, ty0[j]);
            float cx1 = fmaxf(p_x1, tx1[j]), cy1 = fmaxf(p_y1, ty1[j]);
            // boxes have w,h >= 0 -> enclosure extents provably >= 0: no clamp
            float carea = (cx1 - cx0) * (cy1 - cy0);
            float g = u * fast_rcp(carea + EPS);         // (uni+EPS)/(carea+EPS)
            // cost = (2-prob) + 5*cb - 2*iou - 2*g  (constant 2 pre-folded)
            float r = fmaf(COST_BBOX, cb, ccv[j][i]);
            r = fmaf(-2.0f, iou, r);
            res[j] = fmaf(-2.0f, g, r);
        }
        *(vf4*)(out + (size_t)n * T + tbase) = res;   // plain write-back store
    }
}

extern "C" void kernel_launch(void* const* d_in, const int* in_sizes, int n_in,
                              void* d_out, int out_size, void* d_ws, size_t ws_size,
                              hipStream_t stream) {
    const float* class_logits  = (const float*)d_in[0];  // [B,Q,C]
    const float* bbox_coords   = (const float*)d_in[1];  // [B,Q,4]
    const int*   target_labels = (const int*)d_in[2];    // [T]
    const float* target_boxes  = (const float*)d_in[3];  // [T,4]
    float* out = (float*)d_out;

    int N = in_sizes[0] / kC;  // 9600
    int T = in_sizes[2];       // 3200

    float* probsT = (float*)d_ws;   // C*N floats = 422 KB, fully overwritten

    {
        int tpb = 256;
        int blocks = (N + tpb - 1) / tpb;
        softmax_probsT_kernel<<<blocks, tpb, 0, stream>>>(class_logits, probsT, N);
    }
    {
        dim3 grid((T / 4 + TPB - 1) / TPB, N / NPT);
        cost_matrix_kernel<<<grid, TPB, 0, stream>>>(probsT, bbox_coords,
                                                     target_labels, target_boxes,
                                                     out, N, T);
    }
}